// Round 12
// baseline (216.909 us; speedup 1.0000x reference)
//
#include <hip/hip_runtime.h>
#include <stdint.h>

// ---------- types / helpers ----------
typedef short bf16x8 __attribute__((ext_vector_type(8)));
typedef float f32x4 __attribute__((ext_vector_type(4)));

#define MFMA_BF16(a, b, c) __builtin_amdgcn_mfma_f32_16x16x32_bf16((a), (b), (c), 0, 0, 0)

__device__ __forceinline__ short f2bf(float x) {
  union { float f; uint32_t u; } v; v.f = x;
  uint32_t r = (v.u + 0x7FFFu + ((v.u >> 16) & 1u)) >> 16;  // RNE
  return (short)r;
}
__device__ __forceinline__ uint32_t rnd_bf_hi(float x) {  // rounded bits, bf16 in high half
  union { float f; uint32_t u; } v; v.f = x;
  return v.u + 0x7FFFu + ((v.u >> 16) & 1u);
}
__device__ __forceinline__ uint32_t pack2bf(float a, float b) {
  // D = [bf16(b) : bf16(a)]  via byte-select (low half = a)
  return __builtin_amdgcn_perm(rnd_bf_hi(b), rnd_bf_hi(a), 0x07060302);
}
__device__ __forceinline__ float fexp2(float x) {
#if __has_builtin(__builtin_amdgcn_exp2f)
  return __builtin_amdgcn_exp2f(x);
#else
  return __expf(x * 0.6931471805599453f);
#endif
}
__device__ __forceinline__ void async16(const void* g, void* l) {
  __builtin_amdgcn_global_load_lds(
      (const __attribute__((address_space(1))) uint32_t*)g,
      (__attribute__((address_space(3))) uint32_t*)l, 16, 0, 0);
}

// ---------- prep: fp32->bf16 casts + gates context GEMV + mV zeroing ----------
__global__ __launch_bounds__(256) void prep_k(
    const float* __restrict__ x, const float* __restrict__ Wq,
    const float* __restrict__ Wk, const float* __restrict__ Wv,
    const float* __restrict__ Wo, const float* __restrict__ bq,
    short* __restrict__ xb, short* __restrict__ Wqb, short* __restrict__ Wkb,
    short* __restrict__ Wvb, short* __restrict__ Wob, float* __restrict__ ctx,
    float* __restrict__ mV) {
  __shared__ float xs[1024];
  const int bid = blockIdx.x;
  const int tid = threadIdx.x;
  if (bid >= 8256) {
    // zero mV[64][64] (workspace is poison-filled; qkv atomically accumulates)
    float4 z = {0.f, 0.f, 0.f, 0.f};
    ((float4*)mV)[tid] = z;
    ((float4*)mV)[tid + 256] = z;
    ((float4*)mV)[tid + 512] = z;
    ((float4*)mV)[tid + 768] = z;
    return;
  }
  if (bid < 8192) {
    const float* src; short* dst; int idx;
    if (bid < 4096) {
      src = x; dst = xb; idx = (bid << 8) + tid;
    } else {
      const int r = bid - 4096;
      const int z = r >> 10;
      src = (z == 0) ? Wq : (z == 1) ? Wk : (z == 2) ? Wv : Wo;
      dst = (z == 0) ? Wqb : (z == 1) ? Wkb : (z == 2) ? Wvb : Wob;
      idx = ((r & 1023) << 8) + tid;
    }
    float4 v = ((const float4*)src)[idx];
    short4 o;
    o.x = f2bf(v.x); o.y = f2bf(v.y); o.z = f2bf(v.z); o.w = f2bf(v.w);
    ((short4*)dst)[idx] = o;
  } else {
    // gates context: ctx[b][n] = x[b,0,:] . Wq[n,:] + bq[n]   (fp32 exact path)
    const int r = bid - 8192;
    const int b = r >> 4;
    const int n0 = (r & 15) << 6;
    for (int i = tid; i < 1024; i += 256) xs[i] = x[b * 1048576 + i];
    __syncthreads();
    const int w = tid >> 6, lane = tid & 63;
    const float4* xv4 = (const float4*)xs;
    for (int rr = 0; rr < 16; ++rr) {
      const int n = n0 + (w << 4) + rr;
      const float4* wrow = (const float4*)(Wq + n * 1024);
      float p = 0.f;
#pragma unroll
      for (int c2 = 0; c2 < 4; ++c2) {
        float4 wv = wrow[lane + (c2 << 6)];
        float4 xv = xv4[lane + (c2 << 6)];
        p += xv.x * wv.x + xv.y * wv.y + xv.z * wv.z + xv.w * wv.w;
      }
#pragma unroll
      for (int off = 32; off; off >>= 1) p += __shfl_xor(p, off);
      if (lane == 0) ctx[b * 1024 + n] = p + bq[n];
    }
  }
}

// ---------- QKV projection: 128x128, double-buffered 1-barrier 2-phase ----------
// V-epilogue additionally accumulates meanV partials (fp32, pre-rounding,
// incl. bias) into mV[bh][dk] via device-scope atomics.
template <bool SWP>
__device__ __forceinline__ void qkv_core128(
    const short* __restrict__ A, const short* __restrict__ W,
    const float* __restrict__ bias, short* __restrict__ out,
    float* __restrict__ mV, short* As, short* Bs, int m0, int n0) {
  const int tid = threadIdx.x;
  const int w = tid >> 6, lane = tid & 63;
  const int m15 = lane & 15, quad = lane >> 4;
  const int wr = w >> 1, wc = w & 1;

  f32x4 acc[4][4];
#pragma unroll
  for (int i = 0; i < 4; ++i)
#pragma unroll
    for (int j = 0; j < 4; ++j) { f32x4 zz = {0.f, 0.f, 0.f, 0.f}; acc[i][j] = zz; }

  const int srow = (w << 5) + (lane >> 2);
  const int sxor = (srow >> 1) & 3;
  const int scol = (((lane & 3) ^ sxor) << 3);
  const short* ga0 = A + (m0 + srow) * 1024 + scol;
  const short* ga1 = ga0 + 16 * 1024;
  const short* gb0 = W + (n0 + srow) * 1024 + scol;
  const short* gb1 = gb0 + 16 * 1024;
  short* la0 = &As[srow * 32 + ((lane & 3) << 3)];
  short* la1 = la0 + 512;
  short* lb0 = &Bs[srow * 32 + ((lane & 3) << 3)];
  short* lb1 = lb0 + 512;

  async16(ga0, la0); async16(ga1, la1);
  async16(gb0, lb0); async16(gb1, lb1);
  __syncthreads();

  for (int kt = 0; kt < 32; ++kt) {
    const int buf = kt & 1;
    if (kt < 31) {
      const int nb = (buf ^ 1) << 12;
      const int off = (kt + 1) << 5;
      async16(ga0 + off, la0 + nb); async16(ga1 + off, la1 + nb);
      async16(gb0 + off, lb0 + nb); async16(gb1 + off, lb1 + nb);
    }
    const short* Ab = As + (buf << 12);
    const short* Bb = Bs + (buf << 12);
    bf16x8 a[4], b[4];
#pragma unroll
    for (int i = 0; i < 4; ++i) {
      const int ra = (wr << 6) + (i << 4) + m15;
      a[i] = *(const bf16x8*)(&Ab[ra * 32 + ((quad ^ ((ra >> 1) & 3)) << 3)]);
    }
#pragma unroll
    for (int j = 0; j < 4; ++j) {
      const int rb = (wc << 6) + (j << 4) + m15;
      b[j] = *(const bf16x8*)(&Bb[rb * 32 + ((quad ^ ((rb >> 1) & 3)) << 3)]);
    }
#pragma unroll
    for (int i = 0; i < 4; ++i)
#pragma unroll
      for (int j = 0; j < 4; ++j) {
        if (SWP) acc[i][j] = MFMA_BF16(b[j], a[i], acc[i][j]);
        else     acc[i][j] = MFMA_BF16(a[i], b[j], acc[i][j]);
      }
    if (kt < 31) __syncthreads();
  }

  if (SWP) {
    // C^T: lane m15 = x-row (t), quad*4+r = W-row (dk) -> packed along dk.
#pragma unroll
    for (int j = 0; j < 4; ++j) {
      const int n = n0 + (wc << 6) + (j << 4) + (quad << 2);
      const float4 bv = *(const float4*)(bias + n);
      const int hh = n >> 6, dk0 = n & 63;
#pragma unroll
      for (int i = 0; i < 4; ++i) {
        const int m = m0 + (wr << 6) + (i << 4) + m15;
        const int bb = m >> 10, tt = m & 1023;
        uint2 st;
        st.x = pack2bf(acc[i][j][0] + bv.x, acc[i][j][1] + bv.y);
        st.y = pack2bf(acc[i][j][2] + bv.z, acc[i][j][3] + bv.w);
        *(uint2*)(out + (((bb << 4) + hh) << 16) + (tt << 6) + dk0) = st;
      }
    }
  } else {
    // V^T: lane m15 = W-row (dk), quad*4+r = x-row (t) -> packed along t.
#pragma unroll
    for (int j = 0; j < 4; ++j) {
      const int n = n0 + (wc << 6) + (j << 4) + m15;
      const float bv = bias[n];
      const int hh = n >> 6, dk = n & 63;
#pragma unroll
      for (int i = 0; i < 4; ++i) {
        const int m = m0 + (wr << 6) + (i << 4) + (quad << 2);
        const int bb = m >> 10, t0 = m & 1023;
        uint2 st;
        st.x = pack2bf(acc[i][j][0] + bv, acc[i][j][1] + bv);
        st.y = pack2bf(acc[i][j][2] + bv, acc[i][j][3] + bv);
        *(uint2*)(out + (((bb << 4) + hh) << 16) + (dk << 10) + t0) = st;
      }
    }
    // meanV partials: this block covers 128 t-rows of one batch.
    // Per thread, j: 16 t-values (i,r) + 16*bias; quad-reduce (xor 16/32)
    // covers 64 t; both wr-waves atomically add -> 128-t block total.
    {
      const int bb = m0 >> 10;
#pragma unroll
      for (int j = 0; j < 4; ++j) {
        const int n = n0 + (wc << 6) + (j << 4) + m15;
        float s = 16.0f * bias[n];
#pragma unroll
        for (int i = 0; i < 4; ++i)
          s += (acc[i][j][0] + acc[i][j][1]) + (acc[i][j][2] + acc[i][j][3]);
        s += __shfl_xor(s, 16);
        s += __shfl_xor(s, 32);
        if (quad == 0) {
          const int hh = n >> 6, dk = n & 63;
          atomicAdd(&mV[(((bb << 4) + hh) << 6) + dk], s);
        }
      }
    }
  }
}

// Fused launch: blocks 0..767 = QKV GEMM tiles; block 768 = gates finisher
__global__ __launch_bounds__(256) void gemm_qkv(
    const short* __restrict__ xb,
    const short* __restrict__ Wqb, const short* __restrict__ Wkb, const short* __restrict__ Wvb,
    const float* __restrict__ bq, const float* __restrict__ bk, const float* __restrict__ bv,
    short* __restrict__ Qh, short* __restrict__ Kh, short* __restrict__ Vt,
    float* __restrict__ mV,
    const float* __restrict__ ctx, const float* __restrict__ Wg1,
    const float* __restrict__ bg1, const float* __restrict__ Wg2,
    const float* __restrict__ bg2, float* __restrict__ gates,
    float* __restrict__ u_out) {
  __shared__ short As[8192];   // 2 x (128x32) bf16
  __shared__ short Bs[8192];
  const int bid = blockIdx.x;
  if (bid < 768) {
    const int z = bid >> 8;
    const int r = bid & 255;
    const int m0 = (r & 31) << 7, n0 = (r >> 5) << 7;
    if (z == 0)      qkv_core128<true >(xb, Wqb, bq, Qh, mV, As, Bs, m0, n0);
    else if (z == 1) qkv_core128<true >(xb, Wkb, bk, Kh, mV, As, Bs, m0, n0);
    else             qkv_core128<false>(xb, Wvb, bv, Vt, mV, As, Bs, m0, n0);
    return;
  }
  // ---- gates finisher (reuses As for reduction scratch) ----
  float* red = (float*)As;
  const int tid = threadIdx.x, w = tid >> 6, lane = tid & 63;
  for (int b = 0; b < 4; ++b) {
    float4 cv = ((const float4*)(ctx + b * 1024))[tid];
    float4 w1 = ((const float4*)Wg1)[tid];
    float4 w2 = ((const float4*)Wg2)[tid];
    float p1 = cv.x * w1.x + cv.y * w1.y + cv.z * w1.z + cv.w * w1.w;
    float p2 = cv.x * w2.x + cv.y * w2.y + cv.z * w2.z + cv.w * w2.w;
#pragma unroll
    for (int off = 32; off; off >>= 1) { p1 += __shfl_xor(p1, off); p2 += __shfl_xor(p2, off); }
    if (lane == 0) { red[w] = p1; red[8 + w] = p2; }
    __syncthreads();
    if (tid == 0) {
      float g1 = red[0] + red[1] + red[2] + red[3] + bg1[0];
      float g2 = red[8] + red[9] + red[10] + red[11] + bg2[0];
      float q1 = 1.f / (1.f + expf(-g1));
      float q2 = 1.f / (1.f + expf(-g2));
      float c = fminf(fmaxf(q1 * q2, 1e-8f), 1.0f);
      gates[b * 2 + 0] = c;
      gates[b * 2 + 1] = (c < 0.3f ? c : 1.0f) * 0.125f * 1.4426950408889634f;
      u_out[b] = 1.0f - c;
    }
    __syncthreads();
  }
}

// ---------- output projection: 64x128 tile dbuf -> 512 blocks (2/CU) ----------
__global__ __launch_bounds__(256) void gemm_out(const short* __restrict__ Ab_,
                                                const short* __restrict__ Wo,
                                                const float* __restrict__ bo,
                                                float* __restrict__ Cout) {
  const int m0 = blockIdx.x << 6;
  const int n0 = blockIdx.y << 7;
  const int tid = threadIdx.x;
  const int w = tid >> 6, lane = tid & 63;
  const int m15 = lane & 15, quad = lane >> 4;
  const int wr = w >> 1, wc = w & 1;

  __shared__ short As[4096];   // 2 x (64x32)
  __shared__ short Bs[8192];   // 2 x (128x32)

  f32x4 acc[2][4];
#pragma unroll
  for (int i = 0; i < 2; ++i)
#pragma unroll
    for (int j = 0; j < 4; ++j) { f32x4 zz = {0.f, 0.f, 0.f, 0.f}; acc[i][j] = zz; }

  const int arow = (w << 4) + (lane >> 2);               // 0..63
  const int axor = (arow >> 1) & 3;
  const short* gaA = Ab_ + (m0 + arow) * 1024 + (((lane & 3) ^ axor) << 3);
  short* laA = &As[arow * 32 + ((lane & 3) << 3)];
  const int brow = (w << 5) + (lane >> 2);               // rows brow, brow+16
  const int bxor = (brow >> 1) & 3;
  const short* gb0 = Wo + (n0 + brow) * 1024 + (((lane & 3) ^ bxor) << 3);
  const short* gb1 = gb0 + 16 * 1024;
  short* lb0 = &Bs[brow * 32 + ((lane & 3) << 3)];
  short* lb1 = lb0 + 512;

  async16(gaA, laA);
  async16(gb0, lb0); async16(gb1, lb1);
  __syncthreads();

  for (int kt = 0; kt < 32; ++kt) {
    const int buf = kt & 1;
    if (kt < 31) {
      const int off = (kt + 1) << 5;
      async16(gaA + off, laA + ((buf ^ 1) << 11));
      async16(gb0 + off, lb0 + ((buf ^ 1) << 12));
      async16(gb1 + off, lb1 + ((buf ^ 1) << 12));
    }
    const short* Ab = As + (buf << 11);
    const short* Bb = Bs + (buf << 12);
    bf16x8 a[2], b[4];
#pragma unroll
    for (int i = 0; i < 2; ++i) {
      const int ra = (wr << 5) + (i << 4) + m15;
      a[i] = *(const bf16x8*)(&Ab[ra * 32 + ((quad ^ ((ra >> 1) & 3)) << 3)]);
    }
#pragma unroll
    for (int j = 0; j < 4; ++j) {
      const int rb = (wc << 6) + (j << 4) + m15;
      b[j] = *(const bf16x8*)(&Bb[rb * 32 + ((quad ^ ((rb >> 1) & 3)) << 3)]);
    }
#pragma unroll
    for (int i = 0; i < 2; ++i)
#pragma unroll
      for (int j = 0; j < 4; ++j)
        acc[i][j] = MFMA_BF16(a[i], b[j], acc[i][j]);
    if (kt < 31) __syncthreads();
  }

#pragma unroll
  for (int j = 0; j < 4; ++j) {
    const int n = n0 + (wc << 6) + (j << 4) + m15;
    const float bb_ = bo[n];
#pragma unroll
    for (int i = 0; i < 2; ++i) {
      const int mb = m0 + (wr << 5) + (i << 4) + (quad << 2);
#pragma unroll
      for (int r = 0; r < 4; ++r)
        Cout[(mb + r) * 1024 + n] = acc[i][j][r] + bb_;
    }
  }
}

// ---------- flash attention: QBLK=64, defer-PV, precomputed mV, 4 blocks/CU ----------
// Iter t: STAGE(t+1) | QK[t] | PV[t-1] (pf_prev regs, Vs[(t-1)%3]) | softmax[t].
__global__ __launch_bounds__(256, 4) void attn_k(const short* __restrict__ Qh,
                                                 const short* __restrict__ Kh,
                                                 const short* __restrict__ Vt,
                                                 const float* __restrict__ gates,
                                                 const float* __restrict__ mV,
                                                 short* __restrict__ attnb) {
  const int bh = blockIdx.x;
  const int b = bh >> 4, h = bh & 15;
  const int q0 = blockIdx.y << 6;
  const int tid = threadIdx.x;
  const int w = tid >> 6, lane = tid & 63;
  const int m15 = lane & 15, quad = lane >> 4;

  __shared__ short Ks[2][4096];  // [64 k][64 d], 8-short chunks XOR-swizzled by row&7
  __shared__ short Vs[3][4096];  // [64 d][64 t], same swizzle, triple-buffered

  const short* ksrc = Kh + bh * 65536;
  const short* vsrc = Vt + bh * 65536;

  const float sl = gates[b * 2 + 1];

  const short* qsrc = Qh + ((bh << 10) + q0 + (w << 4) + m15) * 64;
  const bf16x8 qb0 = *(const bf16x8*)(qsrc + (quad << 3));
  const bf16x8 qb1 = *(const bf16x8*)(qsrc + 32 + (quad << 3));

  const int off0 = tid, off1 = tid + 256;
  const int r0 = off0 >> 3, cb0 = (off0 & 7) ^ (r0 & 7);
  const int r1 = off1 >> 3, cb1 = (off1 & 7) ^ (r1 & 7);

#define STAGE(kv, kb, vb)                                                      \
  do {                                                                         \
    async16(ksrc + (((kv) << 6) + r0) * 64 + (cb0 << 3), &Ks[kb][off0 << 3]);  \
    async16(ksrc + (((kv) << 6) + r1) * 64 + (cb1 << 3), &Ks[kb][off1 << 3]);  \
    async16(vsrc + r0 * 1024 + ((kv) << 6) + (cb0 << 3), &Vs[vb][off0 << 3]);  \
    async16(vsrc + r1 * 1024 + ((kv) << 6) + (cb1 << 3), &Vs[vb][off1 << 3]);  \
  } while (0)

  STAGE(0, 0, 0);

  float lsum = 0.f;
  f32x4 oA[4];
#pragma unroll
  for (int jd = 0; jd < 4; ++jd) { f32x4 zz = {0.f, 0.f, 0.f, 0.f}; oA[jd] = zz; }

  const int srcA = ((quad & 1) << 5) + m15;
  const int srcB = srcA + 16;
  const bool selhi = (quad & 2) != 0;

#define BUILD_PF(pf, pk)                                                       \
  do {                                                                         \
    _Pragma("unroll")                                                          \
    for (int Hh = 0; Hh < 2; ++Hh) {                                           \
      uint32_t f[4];                                                           \
      _Pragma("unroll")                                                        \
      for (int rp = 0; rp < 2; ++rp) {                                         \
        uint32_t alo = (uint32_t)__shfl((int)pk[2 * Hh][rp], srcA);            \
        uint32_t ahi = (uint32_t)__shfl((int)pk[2 * Hh + 1][rp], srcA);        \
        uint32_t blo = (uint32_t)__shfl((int)pk[2 * Hh][rp], srcB);            \
        uint32_t bhi = (uint32_t)__shfl((int)pk[2 * Hh + 1][rp], srcB);        \
        f[rp]     = selhi ? ahi : alo;                                         \
        f[2 + rp] = selhi ? bhi : blo;                                         \
      }                                                                        \
      pf[Hh] = *(bf16x8*)f;                                                    \
    }                                                                          \
  } while (0)

#define PV_STEP(Vb, pfa)                                                       \
  do {                                                                         \
    _Pragma("unroll")                                                          \
    for (int jd = 0; jd < 4; ++jd) {                                           \
      const int row = (jd << 4) + m15;                                         \
      const int sw = row & 7;                                                  \
      bf16x8 v0 = *(const bf16x8*)((Vb) + (row << 6) + ((quad ^ sw) << 3));    \
      bf16x8 v1 = *(const bf16x8*)((Vb) + (row << 6) + (((quad + 4) ^ sw) << 3)); \
      oA[jd] = MFMA_BF16(v0, pfa[0], oA[jd]);                                  \
      oA[jd] = MFMA_BF16(v1, pfa[1], oA[jd]);                                  \
    }                                                                          \
  } while (0)

  bf16x8 pfp[2];
  pfp[0] = (bf16x8){0, 0, 0, 0, 0, 0, 0, 0};
  pfp[1] = pfp[0];

  for (int kv = 0; kv < 16; ++kv) {
    __syncthreads();  // Ks[kv&1]/Vs[kv%3] landed; prior reads done
    if (kv < 15) STAGE(kv + 1, (kv + 1) & 1, (kv + 1) % 3);
    const short* Kb = &Ks[kv & 1][0];

    // --- QK[kv] ---
    f32x4 sA[4];
#pragma unroll
    for (int s = 0; s < 4; ++s) {
      const int row = (s << 4) + m15;
      const int sw = row & 7;
      bf16x8 a0 = *(const bf16x8*)(Kb + (row << 6) + ((quad ^ sw) << 3));
      bf16x8 a1 = *(const bf16x8*)(Kb + (row << 6) + (((quad + 4) ^ sw) << 3));
      f32x4 zz = {0.f, 0.f, 0.f, 0.f};
      zz = MFMA_BF16(a0, qb0, zz);
      zz = MFMA_BF16(a1, qb1, zz);
      sA[s] = zz;
    }

    // --- PV[kv-1] (independent of QK[kv] and softmax below) ---
    if (kv > 0) {
      const short* Vb = &Vs[(kv - 1) % 3][0];
      PV_STEP(Vb, pfp);
    }

    // --- softmax[kv] ---
    uint32_t pk[4][2];
#pragma unroll
    for (int s = 0; s < 4; ++s) {
      float p0 = fexp2(sA[s][0] * sl);
      float p1 = fexp2(sA[s][1] * sl);
      float p2 = fexp2(sA[s][2] * sl);
      float p3 = fexp2(sA[s][3] * sl);
      lsum += (p0 + p1) + (p2 + p3);
      pk[s][0] = pack2bf(p0, p1);
      pk[s][1] = pack2bf(p2, p3);
    }

    bf16x8 pf[2];
    BUILD_PF(pf, pk);
    pfp[0] = pf[0]; pfp[1] = pf[1];
  }

  // --- epilogue PV[15]: Vs[0], staged at kv=14, drained by kv=15 barrier ---
  {
    const short* Vb = &Vs[15 % 3][0];
    PV_STEP(Vb, pfp);
  }
#undef STAGE
#undef BUILD_PF
#undef PV_STEP

  float l = lsum;
  l += __shfl_xor(l, 16);
  l += __shfl_xor(l, 32);

  const float cg = gates[b * 2 + 0];
  const float sc0 = cg / l;
  const float coef = (1.0f - cg) * (1.0f / 1024.0f);  // mV holds raw sums over t
  const int qrow = q0 + (w << 4) + m15;
  short* orow = attnb + ((b << 10) + qrow) * 1024 + (h << 6);
#pragma unroll
  for (int jd = 0; jd < 4; ++jd) {
    float4 mv = *(const float4*)(mV + (bh << 6) + (jd << 4) + (quad << 2));
    uint2 st;
    st.x = pack2bf(sc0 * oA[jd][0] + coef * mv.x,
                   sc0 * oA[jd][1] + coef * mv.y);
    st.y = pack2bf(sc0 * oA[jd][2] + coef * mv.z,
                   sc0 * oA[jd][3] + coef * mv.w);
    *(uint2*)(orow + (jd << 4) + (quad << 2)) = st;
  }
}

// ---------- launch ----------
extern "C" void kernel_launch(void* const* d_in, const int* in_sizes, int n_in,
                              void* d_out, int out_size, void* d_ws, size_t ws_size,
                              hipStream_t stream) {
  const float* x   = (const float*)d_in[0];
  const float* Wq  = (const float*)d_in[1];
  const float* bq  = (const float*)d_in[2];
  const float* Wk  = (const float*)d_in[3];
  const float* bk  = (const float*)d_in[4];
  const float* Wv  = (const float*)d_in[5];
  const float* bv  = (const float*)d_in[6];
  const float* Wo  = (const float*)d_in[7];
  const float* bo  = (const float*)d_in[8];
  const float* Wg1 = (const float*)d_in[9];
  const float* bg1 = (const float*)d_in[10];
  const float* Wg2 = (const float*)d_in[11];
  const float* bg2 = (const float*)d_in[12];
  float* out = (float*)d_out;

  char* ws = (char*)d_ws;
  short* xb   = (short*)(ws + 0);          //  8 MB  x bf16 [4096][1024]
  short* Wqb  = (short*)(ws + 8388608);    //  2 MB
  short* Wkb  = (short*)(ws + 10485760);   //  2 MB
  short* Wvb  = (short*)(ws + 12582912);   //  2 MB
  short* Wob  = (short*)(ws + 14680064);   //  2 MB
  short* Qh   = (short*)(ws + 16777216);   //  8 MB  [BH][T][64]
  short* Kh   = (short*)(ws + 25165824);   //  8 MB  [BH][T][64]
  short* Vt   = (short*)(ws + 33554432);   //  8 MB  [BH][64][T]
  short* attb = (short*)(ws + 41943040);   //  8 MB  [4096][1024]
  float* ctx  = (float*)(ws + 50331648);   // 16 KB
  float* gat  = (float*)(ws + 50348032);   // 32 B   [B][{c, scale*log2e}]
  float* mV   = (float*)(ws + 50348064);   // 16 KB  [BH][64] raw sums

  prep_k<<<8257, 256, 0, stream>>>(x, Wq, Wk, Wv, Wo, bq,
                                   xb, Wqb, Wkb, Wvb, Wob, ctx, mV);
  gemm_qkv<<<769, 256, 0, stream>>>(xb, Wqb, Wkb, Wvb, bq, bk, bv,
                                    Qh, Kh, Vt, mV,
                                    ctx, Wg1, bg1, Wg2, bg2, gat,
                                    out + 4194304);
  attn_k<<<dim3(64, 16), 256, 0, stream>>>(Qh, Kh, Vt, gat, mV, attb);
  gemm_out<<<dim3(64, 8), 256, 0, stream>>>(attb, Wob, bo, out);
}

// Round 13
// 216.029 us; speedup vs baseline: 1.0041x; 1.0041x over previous
//
#include <hip/hip_runtime.h>
#include <stdint.h>

// ---------- types / helpers ----------
typedef short bf16x8 __attribute__((ext_vector_type(8)));
typedef float f32x4 __attribute__((ext_vector_type(4)));

#define MFMA_BF16(a, b, c) __builtin_amdgcn_mfma_f32_16x16x32_bf16((a), (b), (c), 0, 0, 0)

__device__ __forceinline__ short f2bf(float x) {
  union { float f; uint32_t u; } v; v.f = x;
  uint32_t r = (v.u + 0x7FFFu + ((v.u >> 16) & 1u)) >> 16;  // RNE
  return (short)r;
}
__device__ __forceinline__ uint32_t rnd_bf_hi(float x) {  // rounded bits, bf16 in high half
  union { float f; uint32_t u; } v; v.f = x;
  return v.u + 0x7FFFu + ((v.u >> 16) & 1u);
}
__device__ __forceinline__ uint32_t pack2bf(float a, float b) {
  // D = [bf16(b) : bf16(a)]  via byte-select (low half = a)
  return __builtin_amdgcn_perm(rnd_bf_hi(b), rnd_bf_hi(a), 0x07060302);
}
__device__ __forceinline__ float fexp2(float x) {
#if __has_builtin(__builtin_amdgcn_exp2f)
  return __builtin_amdgcn_exp2f(x);
#else
  return __expf(x * 0.6931471805599453f);
#endif
}
__device__ __forceinline__ void async16(const void* g, void* l) {
  __builtin_amdgcn_global_load_lds(
      (const __attribute__((address_space(1))) uint32_t*)g,
      (__attribute__((address_space(3))) uint32_t*)l, 16, 0, 0);
}

// ---------- prep: fused fp32->bf16 casts + gates context GEMV ----------
__global__ __launch_bounds__(256) void prep_k(
    const float* __restrict__ x, const float* __restrict__ Wq,
    const float* __restrict__ Wk, const float* __restrict__ Wv,
    const float* __restrict__ Wo, const float* __restrict__ bq,
    short* __restrict__ xb, short* __restrict__ Wqb, short* __restrict__ Wkb,
    short* __restrict__ Wvb, short* __restrict__ Wob, float* __restrict__ ctx) {
  __shared__ float xs[1024];
  const int bid = blockIdx.x;
  const int tid = threadIdx.x;
  if (bid < 8192) {
    const float* src; short* dst; int idx;
    if (bid < 4096) {
      src = x; dst = xb; idx = (bid << 8) + tid;
    } else {
      const int r = bid - 4096;
      const int z = r >> 10;
      src = (z == 0) ? Wq : (z == 1) ? Wk : (z == 2) ? Wv : Wo;
      dst = (z == 0) ? Wqb : (z == 1) ? Wkb : (z == 2) ? Wvb : Wob;
      idx = ((r & 1023) << 8) + tid;
    }
    float4 v = ((const float4*)src)[idx];
    short4 o;
    o.x = f2bf(v.x); o.y = f2bf(v.y); o.z = f2bf(v.z); o.w = f2bf(v.w);
    ((short4*)dst)[idx] = o;
  } else {
    // gates context: ctx[b][n] = x[b,0,:] . Wq[n,:] + bq[n]   (fp32 exact path)
    const int r = bid - 8192;
    const int b = r >> 4;
    const int n0 = (r & 15) << 6;
    for (int i = tid; i < 1024; i += 256) xs[i] = x[b * 1048576 + i];
    __syncthreads();
    const int w = tid >> 6, lane = tid & 63;
    const float4* xv4 = (const float4*)xs;
    for (int rr = 0; rr < 16; ++rr) {
      const int n = n0 + (w << 4) + rr;
      const float4* wrow = (const float4*)(Wq + n * 1024);
      float p = 0.f;
#pragma unroll
      for (int c2 = 0; c2 < 4; ++c2) {
        float4 wv = wrow[lane + (c2 << 6)];
        float4 xv = xv4[lane + (c2 << 6)];
        p += xv.x * wv.x + xv.y * wv.y + xv.z * wv.z + xv.w * wv.w;
      }
#pragma unroll
      for (int off = 32; off; off >>= 1) p += __shfl_xor(p, off);
      if (lane == 0) ctx[b * 1024 + n] = p + bq[n];
    }
  }
}

// ---------- QKV projection: 64x128 tile, double-buffered 1-barrier ----------
// Smaller tile -> 1536 blocks, 24 KB LDS -> up to 6 blocks/CU (occupancy fix).
// Conflict-free LDS (chunk ^= (row>>1)&3), packed 8B epilogues (MM-swap Q/K).
template <bool SWP>
__device__ __forceinline__ void qkv_core64(
    const short* __restrict__ A, const short* __restrict__ W,
    const float* __restrict__ bias, short* __restrict__ out,
    short* As, short* Bs, int m0, int n0) {
  const int tid = threadIdx.x;
  const int w = tid >> 6, lane = tid & 63;
  const int m15 = lane & 15, quad = lane >> 4;
  const int wr = w >> 1, wc = w & 1;

  f32x4 acc[2][4];
#pragma unroll
  for (int i = 0; i < 2; ++i)
#pragma unroll
    for (int j = 0; j < 4; ++j) { f32x4 zz = {0.f, 0.f, 0.f, 0.f}; acc[i][j] = zz; }

  // A staging: 64 rows, one async16/thread
  const int arow = (w << 4) + (lane >> 2);               // 0..63
  const int axor = (arow >> 1) & 3;
  const short* gaA = A + (m0 + arow) * 1024 + (((lane & 3) ^ axor) << 3);
  short* laA = &As[arow * 32 + ((lane & 3) << 3)];
  // B staging: 128 rows, two async16/thread
  const int brow = (w << 5) + (lane >> 2);               // rows brow, brow+16
  const int bxor = (brow >> 1) & 3;
  const short* gb0 = W + (n0 + brow) * 1024 + (((lane & 3) ^ bxor) << 3);
  const short* gb1 = gb0 + 16 * 1024;
  short* lb0 = &Bs[brow * 32 + ((lane & 3) << 3)];
  short* lb1 = lb0 + 512;

  async16(gaA, laA);
  async16(gb0, lb0); async16(gb1, lb1);
  __syncthreads();

  for (int kt = 0; kt < 32; ++kt) {
    const int buf = kt & 1;
    if (kt < 31) {
      const int off = (kt + 1) << 5;
      async16(gaA + off, laA + ((buf ^ 1) << 11));
      async16(gb0 + off, lb0 + ((buf ^ 1) << 12));
      async16(gb1 + off, lb1 + ((buf ^ 1) << 12));
    }
    const short* Ab = As + (buf << 11);
    const short* Bb = Bs + (buf << 12);
    bf16x8 a[2], b[4];
#pragma unroll
    for (int i = 0; i < 2; ++i) {
      const int ra = (wr << 5) + (i << 4) + m15;
      a[i] = *(const bf16x8*)(&Ab[ra * 32 + ((quad ^ ((ra >> 1) & 3)) << 3)]);
    }
#pragma unroll
    for (int j = 0; j < 4; ++j) {
      const int rb = (wc << 6) + (j << 4) + m15;
      b[j] = *(const bf16x8*)(&Bb[rb * 32 + ((quad ^ ((rb >> 1) & 3)) << 3)]);
    }
#pragma unroll
    for (int i = 0; i < 2; ++i)
#pragma unroll
      for (int j = 0; j < 4; ++j) {
        if (SWP) acc[i][j] = MFMA_BF16(b[j], a[i], acc[i][j]);
        else     acc[i][j] = MFMA_BF16(a[i], b[j], acc[i][j]);
      }
    if (kt < 31) __syncthreads();
  }

  if (SWP) {
    // C^T: lane m15 = x-row (t), quad*4+r = W-row (dk) -> packed along dk.
#pragma unroll
    for (int j = 0; j < 4; ++j) {
      const int n = n0 + (wc << 6) + (j << 4) + (quad << 2);
      const float4 bv = *(const float4*)(bias + n);
      const int hh = n >> 6, dk0 = n & 63;
#pragma unroll
      for (int i = 0; i < 2; ++i) {
        const int m = m0 + (wr << 5) + (i << 4) + m15;
        const int bb = m >> 10, tt = m & 1023;
        uint2 st;
        st.x = pack2bf(acc[i][j][0] + bv.x, acc[i][j][1] + bv.y);
        st.y = pack2bf(acc[i][j][2] + bv.z, acc[i][j][3] + bv.w);
        *(uint2*)(out + (((bb << 4) + hh) << 16) + (tt << 6) + dk0) = st;
      }
    }
  } else {
    // V^T: lane m15 = W-row (dk), quad*4+r = x-row (t) -> packed along t.
#pragma unroll
    for (int j = 0; j < 4; ++j) {
      const int n = n0 + (wc << 6) + (j << 4) + m15;
      const float bv = bias[n];
      const int hh = n >> 6, dk = n & 63;
#pragma unroll
      for (int i = 0; i < 2; ++i) {
        const int m = m0 + (wr << 5) + (i << 4) + (quad << 2);
        const int bb = m >> 10, t0 = m & 1023;
        uint2 st;
        st.x = pack2bf(acc[i][j][0] + bv, acc[i][j][1] + bv);
        st.y = pack2bf(acc[i][j][2] + bv, acc[i][j][3] + bv);
        *(uint2*)(out + (((bb << 4) + hh) << 16) + (dk << 10) + t0) = st;
      }
    }
  }
}

// Fused launch: blocks 0..1535 = QKV GEMM tiles; block 1536 = gates finisher
__global__ __launch_bounds__(256) void gemm_qkv(
    const short* __restrict__ xb,
    const short* __restrict__ Wqb, const short* __restrict__ Wkb, const short* __restrict__ Wvb,
    const float* __restrict__ bq, const float* __restrict__ bk, const float* __restrict__ bv,
    short* __restrict__ Qh, short* __restrict__ Kh, short* __restrict__ Vt,
    const float* __restrict__ ctx, const float* __restrict__ Wg1,
    const float* __restrict__ bg1, const float* __restrict__ Wg2,
    const float* __restrict__ bg2, float* __restrict__ gates,
    float* __restrict__ u_out) {
  __shared__ short As[4096];   // 2 x (64x32) bf16
  __shared__ short Bs[8192];   // 2 x (128x32) bf16
  const int bid = blockIdx.x;
  if (bid < 1536) {
    const int z = bid >> 9;
    const int r = bid & 511;
    const int m0 = (r & 63) << 6, n0 = (r >> 6) << 7;
    if (z == 0)      qkv_core64<true >(xb, Wqb, bq, Qh, As, Bs, m0, n0);
    else if (z == 1) qkv_core64<true >(xb, Wkb, bk, Kh, As, Bs, m0, n0);
    else             qkv_core64<false>(xb, Wvb, bv, Vt, As, Bs, m0, n0);
    return;
  }
  // ---- gates finisher (reuses As for reduction scratch) ----
  float* red = (float*)As;
  const int tid = threadIdx.x, w = tid >> 6, lane = tid & 63;
  for (int b = 0; b < 4; ++b) {
    float4 cv = ((const float4*)(ctx + b * 1024))[tid];
    float4 w1 = ((const float4*)Wg1)[tid];
    float4 w2 = ((const float4*)Wg2)[tid];
    float p1 = cv.x * w1.x + cv.y * w1.y + cv.z * w1.z + cv.w * w1.w;
    float p2 = cv.x * w2.x + cv.y * w2.y + cv.z * w2.z + cv.w * w2.w;
#pragma unroll
    for (int off = 32; off; off >>= 1) { p1 += __shfl_xor(p1, off); p2 += __shfl_xor(p2, off); }
    if (lane == 0) { red[w] = p1; red[8 + w] = p2; }
    __syncthreads();
    if (tid == 0) {
      float g1 = red[0] + red[1] + red[2] + red[3] + bg1[0];
      float g2 = red[8] + red[9] + red[10] + red[11] + bg2[0];
      float q1 = 1.f / (1.f + expf(-g1));
      float q2 = 1.f / (1.f + expf(-g2));
      float c = fminf(fmaxf(q1 * q2, 1e-8f), 1.0f);
      gates[b * 2 + 0] = c;
      gates[b * 2 + 1] = (c < 0.3f ? c : 1.0f) * 0.125f * 1.4426950408889634f;
      u_out[b] = 1.0f - c;
    }
    __syncthreads();
  }
}

// ---------- output projection: 64x128 tile dbuf -> 512 blocks (2/CU) ----------
__global__ __launch_bounds__(256) void gemm_out(const short* __restrict__ Ab_,
                                                const short* __restrict__ Wo,
                                                const float* __restrict__ bo,
                                                float* __restrict__ Cout) {
  const int m0 = blockIdx.x << 6;
  const int n0 = blockIdx.y << 7;
  const int tid = threadIdx.x;
  const int w = tid >> 6, lane = tid & 63;
  const int m15 = lane & 15, quad = lane >> 4;
  const int wr = w >> 1, wc = w & 1;

  __shared__ short As[4096];   // 2 x (64x32)
  __shared__ short Bs[8192];   // 2 x (128x32)

  f32x4 acc[2][4];
#pragma unroll
  for (int i = 0; i < 2; ++i)
#pragma unroll
    for (int j = 0; j < 4; ++j) { f32x4 zz = {0.f, 0.f, 0.f, 0.f}; acc[i][j] = zz; }

  const int arow = (w << 4) + (lane >> 2);               // 0..63
  const int axor = (arow >> 1) & 3;
  const short* gaA = Ab_ + (m0 + arow) * 1024 + (((lane & 3) ^ axor) << 3);
  short* laA = &As[arow * 32 + ((lane & 3) << 3)];
  const int brow = (w << 5) + (lane >> 2);               // rows brow, brow+16
  const int bxor = (brow >> 1) & 3;
  const short* gb0 = Wo + (n0 + brow) * 1024 + (((lane & 3) ^ bxor) << 3);
  const short* gb1 = gb0 + 16 * 1024;
  short* lb0 = &Bs[brow * 32 + ((lane & 3) << 3)];
  short* lb1 = lb0 + 512;

  async16(gaA, laA);
  async16(gb0, lb0); async16(gb1, lb1);
  __syncthreads();

  for (int kt = 0; kt < 32; ++kt) {
    const int buf = kt & 1;
    if (kt < 31) {
      const int off = (kt + 1) << 5;
      async16(gaA + off, laA + ((buf ^ 1) << 11));
      async16(gb0 + off, lb0 + ((buf ^ 1) << 12));
      async16(gb1 + off, lb1 + ((buf ^ 1) << 12));
    }
    const short* Ab = As + (buf << 11);
    const short* Bb = Bs + (buf << 12);
    bf16x8 a[2], b[4];
#pragma unroll
    for (int i = 0; i < 2; ++i) {
      const int ra = (wr << 5) + (i << 4) + m15;
      a[i] = *(const bf16x8*)(&Ab[ra * 32 + ((quad ^ ((ra >> 1) & 3)) << 3)]);
    }
#pragma unroll
    for (int j = 0; j < 4; ++j) {
      const int rb = (wc << 6) + (j << 4) + m15;
      b[j] = *(const bf16x8*)(&Bb[rb * 32 + ((quad ^ ((rb >> 1) & 3)) << 3)]);
    }
#pragma unroll
    for (int i = 0; i < 2; ++i)
#pragma unroll
      for (int j = 0; j < 4; ++j)
        acc[i][j] = MFMA_BF16(a[i], b[j], acc[i][j]);
    if (kt < 31) __syncthreads();
  }

#pragma unroll
  for (int j = 0; j < 4; ++j) {
    const int n = n0 + (wc << 6) + (j << 4) + m15;
    const float bb_ = bo[n];
#pragma unroll
    for (int i = 0; i < 2; ++i) {
      const int mb = m0 + (wr << 5) + (i << 4) + (quad << 2);
#pragma unroll
      for (int r = 0; r < 4; ++r)
        Cout[(mb + r) * 1024 + n] = acc[i][j][r] + bb_;
    }
  }
}

// ---------- flash attention: QBLK=64, defer-PV, fused meanV, 4 blocks/CU ----------
// Iter t: STAGE(t+1) | QK[t] | PV[t-1] (pf_prev regs, Vs[(t-1)%3]) | softmax[t].
__global__ __launch_bounds__(256, 4) void attn_k(const short* __restrict__ Qh,
                                                 const short* __restrict__ Kh,
                                                 const short* __restrict__ Vt,
                                                 const float* __restrict__ gates,
                                                 short* __restrict__ attnb) {
  const int bh = blockIdx.x;
  const int b = bh >> 4, h = bh & 15;
  const int q0 = blockIdx.y << 6;
  const int tid = threadIdx.x;
  const int w = tid >> 6, lane = tid & 63;
  const int m15 = lane & 15, quad = lane >> 4;

  __shared__ short Ks[2][4096];  // [64 k][64 d], 8-short chunks XOR-swizzled by row&7
  __shared__ short Vs[3][4096];  // [64 d][64 t], same swizzle, triple-buffered

  const short* ksrc = Kh + bh * 65536;
  const short* vsrc = Vt + bh * 65536;

  const float sl = gates[b * 2 + 1];

  const short* qsrc = Qh + ((bh << 10) + q0 + (w << 4) + m15) * 64;
  const bf16x8 qb0 = *(const bf16x8*)(qsrc + (quad << 3));
  const bf16x8 qb1 = *(const bf16x8*)(qsrc + 32 + (quad << 3));

  const bf16x8 vone = {0x3F80, 0x3F80, 0x3F80, 0x3F80, 0x3F80, 0x3F80, 0x3F80, 0x3F80};

  const int off0 = tid, off1 = tid + 256;
  const int r0 = off0 >> 3, cb0 = (off0 & 7) ^ (r0 & 7);
  const int r1 = off1 >> 3, cb1 = (off1 & 7) ^ (r1 & 7);

#define STAGE(kv, kb, vb)                                                      \
  do {                                                                         \
    async16(ksrc + (((kv) << 6) + r0) * 64 + (cb0 << 3), &Ks[kb][off0 << 3]);  \
    async16(ksrc + (((kv) << 6) + r1) * 64 + (cb1 << 3), &Ks[kb][off1 << 3]);  \
    async16(vsrc + r0 * 1024 + ((kv) << 6) + (cb0 << 3), &Vs[vb][off0 << 3]);  \
    async16(vsrc + r1 * 1024 + ((kv) << 6) + (cb1 << 3), &Vs[vb][off1 << 3]);  \
  } while (0)

  STAGE(0, 0, 0);

  float lsum = 0.f;
  f32x4 oA[4], o_mv[4];
#pragma unroll
  for (int jd = 0; jd < 4; ++jd) {
    f32x4 zz = {0.f, 0.f, 0.f, 0.f};
    oA[jd] = zz; o_mv[jd] = zz;
  }

  const int srcA = ((quad & 1) << 5) + m15;
  const int srcB = srcA + 16;
  const bool selhi = (quad & 2) != 0;

#define BUILD_PF(pf, pk)                                                       \
  do {                                                                         \
    _Pragma("unroll")                                                          \
    for (int Hh = 0; Hh < 2; ++Hh) {                                           \
      uint32_t f[4];                                                           \
      _Pragma("unroll")                                                        \
      for (int rp = 0; rp < 2; ++rp) {                                         \
        uint32_t alo = (uint32_t)__shfl((int)pk[2 * Hh][rp], srcA);            \
        uint32_t ahi = (uint32_t)__shfl((int)pk[2 * Hh + 1][rp], srcA);        \
        uint32_t blo = (uint32_t)__shfl((int)pk[2 * Hh][rp], srcB);            \
        uint32_t bhi = (uint32_t)__shfl((int)pk[2 * Hh + 1][rp], srcB);        \
        f[rp]     = selhi ? ahi : alo;                                         \
        f[2 + rp] = selhi ? bhi : blo;                                         \
      }                                                                        \
      pf[Hh] = *(bf16x8*)f;                                                    \
    }                                                                          \
  } while (0)

#define PV_STEP(Vb, pfa)                                                       \
  do {                                                                         \
    _Pragma("unroll")                                                          \
    for (int jd = 0; jd < 4; ++jd) {                                           \
      const int row = (jd << 4) + m15;                                         \
      const int sw = row & 7;                                                  \
      bf16x8 v0 = *(const bf16x8*)((Vb) + (row << 6) + ((quad ^ sw) << 3));    \
      bf16x8 v1 = *(const bf16x8*)((Vb) + (row << 6) + (((quad + 4) ^ sw) << 3)); \
      oA[jd] = MFMA_BF16(v0, pfa[0], oA[jd]);                                  \
      oA[jd] = MFMA_BF16(v1, pfa[1], oA[jd]);                                  \
      o_mv[jd] = MFMA_BF16(v0, vone, o_mv[jd]);                                \
      o_mv[jd] = MFMA_BF16(v1, vone, o_mv[jd]);                                \
    }                                                                          \
  } while (0)

  bf16x8 pfp[2];
  pfp[0] = (bf16x8){0, 0, 0, 0, 0, 0, 0, 0};
  pfp[1] = pfp[0];

  for (int kv = 0; kv < 16; ++kv) {
    __syncthreads();  // Ks[kv&1]/Vs[kv%3] landed; prior reads done
    if (kv < 15) STAGE(kv + 1, (kv + 1) & 1, (kv + 1) % 3);
    const short* Kb = &Ks[kv & 1][0];

    // --- QK[kv] ---
    f32x4 sA[4];
#pragma unroll
    for (int s = 0; s < 4; ++s) {
      const int row = (s << 4) + m15;
      const int sw = row & 7;
      bf16x8 a0 = *(const bf16x8*)(Kb + (row << 6) + ((quad ^ sw) << 3));
      bf16x8 a1 = *(const bf16x8*)(Kb + (row << 6) + (((quad + 4) ^ sw) << 3));
      f32x4 zz = {0.f, 0.f, 0.f, 0.f};
      zz = MFMA_BF16(a0, qb0, zz);
      zz = MFMA_BF16(a1, qb1, zz);
      sA[s] = zz;
    }

    // --- PV[kv-1] (independent of QK[kv] and softmax below) ---
    if (kv > 0) {
      const short* Vb = &Vs[(kv - 1) % 3][0];
      PV_STEP(Vb, pfp);
    }

    // --- softmax[kv] ---
    uint32_t pk[4][2];
#pragma unroll
    for (int s = 0; s < 4; ++s) {
      float p0 = fexp2(sA[s][0] * sl);
      float p1 = fexp2(sA[s][1] * sl);
      float p2 = fexp2(sA[s][2] * sl);
      float p3 = fexp2(sA[s][3] * sl);
      lsum += (p0 + p1) + (p2 + p3);
      pk[s][0] = pack2bf(p0, p1);
      pk[s][1] = pack2bf(p2, p3);
    }

    bf16x8 pf[2];
    BUILD_PF(pf, pk);
    pfp[0] = pf[0]; pfp[1] = pf[1];
  }

  // --- epilogue PV[15]: Vs[0], staged at kv=14, drained by kv=15 barrier ---
  {
    const short* Vb = &Vs[15 % 3][0];
    PV_STEP(Vb, pfp);
  }
#undef STAGE
#undef BUILD_PF
#undef PV_STEP

  float l = lsum;
  l += __shfl_xor(l, 16);
  l += __shfl_xor(l, 32);

  const float cg = gates[b * 2 + 0];
  const float sc0 = cg / l;
  const float coef = (1.0f - cg) * (1.0f / 1024.0f);  // o_mv holds raw sums over t
  const int qrow = q0 + (w << 4) + m15;
  short* orow = attnb + ((b << 10) + qrow) * 1024 + (h << 6);
#pragma unroll
  for (int jd = 0; jd < 4; ++jd) {
    uint2 st;
    st.x = pack2bf(sc0 * oA[jd][0] + coef * o_mv[jd][0],
                   sc0 * oA[jd][1] + coef * o_mv[jd][1]);
    st.y = pack2bf(sc0 * oA[jd][2] + coef * o_mv[jd][2],
                   sc0 * oA[jd][3] + coef * o_mv[jd][3]);
    *(uint2*)(orow + (jd << 4) + (quad << 2)) = st;
  }
}

// ---------- launch ----------
extern "C" void kernel_launch(void* const* d_in, const int* in_sizes, int n_in,
                              void* d_out, int out_size, void* d_ws, size_t ws_size,
                              hipStream_t stream) {
  const float* x   = (const float*)d_in[0];
  const float* Wq  = (const float*)d_in[1];
  const float* bq  = (const float*)d_in[2];
  const float* Wk  = (const float*)d_in[3];
  const float* bk  = (const float*)d_in[4];
  const float* Wv  = (const float*)d_in[5];
  const float* bv  = (const float*)d_in[6];
  const float* Wo  = (const float*)d_in[7];
  const float* bo  = (const float*)d_in[8];
  const float* Wg1 = (const float*)d_in[9];
  const float* bg1 = (const float*)d_in[10];
  const float* Wg2 = (const float*)d_in[11];
  const float* bg2 = (const float*)d_in[12];
  float* out = (float*)d_out;

  char* ws = (char*)d_ws;
  short* xb   = (short*)(ws + 0);          //  8 MB  x bf16 [4096][1024]
  short* Wqb  = (short*)(ws + 8388608);    //  2 MB
  short* Wkb  = (short*)(ws + 10485760);   //  2 MB
  short* Wvb  = (short*)(ws + 12582912);   //  2 MB
  short* Wob  = (short*)(ws + 14680064);   //  2 MB
  short* Qh   = (short*)(ws + 16777216);   //  8 MB  [BH][T][64]
  short* Kh   = (short*)(ws + 25165824);   //  8 MB  [BH][T][64]
  short* Vt   = (short*)(ws + 33554432);   //  8 MB  [BH][64][T]
  short* attb = (short*)(ws + 41943040);   //  8 MB  [4096][1024]
  float* ctx  = (float*)(ws + 50331648);   // 16 KB
  float* gat  = (float*)(ws + 50348032);   // 32 B   [B][{c, scale*log2e}]

  prep_k<<<8256, 256, 0, stream>>>(x, Wq, Wk, Wv, Wo, bq,
                                   xb, Wqb, Wkb, Wvb, Wob, ctx);
  gemm_qkv<<<1537, 256, 0, stream>>>(xb, Wqb, Wkb, Wvb, bq, bk, bv,
                                     Qh, Kh, Vt,
                                     ctx, Wg1, bg1, Wg2, bg2, gat,
                                     out + 4194304);
  attn_k<<<dim3(64, 16), 256, 0, stream>>>(Qh, Kh, Vt, gat, attb);
  gemm_out<<<dim3(64, 8), 256, 0, stream>>>(attb, Wob, bo, out);
}

// Round 14
// 204.815 us; speedup vs baseline: 1.0591x; 1.0548x over previous
//
#include <hip/hip_runtime.h>
#include <stdint.h>

// ---------- types / helpers ----------
typedef short bf16x8 __attribute__((ext_vector_type(8)));
typedef float f32x4 __attribute__((ext_vector_type(4)));

#define MFMA_BF16(a, b, c) __builtin_amdgcn_mfma_f32_16x16x32_bf16((a), (b), (c), 0, 0, 0)

__device__ __forceinline__ short f2bf(float x) {
  union { float f; uint32_t u; } v; v.f = x;
  uint32_t r = (v.u + 0x7FFFu + ((v.u >> 16) & 1u)) >> 16;  // RNE
  return (short)r;
}
__device__ __forceinline__ uint32_t rnd_bf_hi(float x) {  // rounded bits, bf16 in high half
  union { float f; uint32_t u; } v; v.f = x;
  return v.u + 0x7FFFu + ((v.u >> 16) & 1u);
}
__device__ __forceinline__ uint32_t pack2bf(float a, float b) {
  // D = [bf16(b) : bf16(a)]  via byte-select (low half = a)
  return __builtin_amdgcn_perm(rnd_bf_hi(b), rnd_bf_hi(a), 0x07060302);
}
__device__ __forceinline__ float fexp2(float x) {
#if __has_builtin(__builtin_amdgcn_exp2f)
  return __builtin_amdgcn_exp2f(x);
#else
  return __expf(x * 0.6931471805599453f);
#endif
}
__device__ __forceinline__ void async16(const void* g, void* l) {
  __builtin_amdgcn_global_load_lds(
      (const __attribute__((address_space(1))) uint32_t*)g,
      (__attribute__((address_space(3))) uint32_t*)l, 16, 0, 0);
}

// ---------- prep: fused fp32->bf16 casts + gates context GEMV ----------
__global__ __launch_bounds__(256) void prep_k(
    const float* __restrict__ x, const float* __restrict__ Wq,
    const float* __restrict__ Wk, const float* __restrict__ Wv,
    const float* __restrict__ Wo, const float* __restrict__ bq,
    short* __restrict__ xb, short* __restrict__ Wqb, short* __restrict__ Wkb,
    short* __restrict__ Wvb, short* __restrict__ Wob, float* __restrict__ ctx) {
  __shared__ float xs[1024];
  const int bid = blockIdx.x;
  const int tid = threadIdx.x;
  if (bid < 8192) {
    const float* src; short* dst; int idx;
    if (bid < 4096) {
      src = x; dst = xb; idx = (bid << 8) + tid;
    } else {
      const int r = bid - 4096;
      const int z = r >> 10;
      src = (z == 0) ? Wq : (z == 1) ? Wk : (z == 2) ? Wv : Wo;
      dst = (z == 0) ? Wqb : (z == 1) ? Wkb : (z == 2) ? Wvb : Wob;
      idx = ((r & 1023) << 8) + tid;
    }
    float4 v = ((const float4*)src)[idx];
    short4 o;
    o.x = f2bf(v.x); o.y = f2bf(v.y); o.z = f2bf(v.z); o.w = f2bf(v.w);
    ((short4*)dst)[idx] = o;
  } else {
    // gates context: ctx[b][n] = x[b,0,:] . Wq[n,:] + bq[n]   (fp32 exact path)
    const int r = bid - 8192;
    const int b = r >> 4;
    const int n0 = (r & 15) << 6;
    for (int i = tid; i < 1024; i += 256) xs[i] = x[b * 1048576 + i];
    __syncthreads();
    const int w = tid >> 6, lane = tid & 63;
    const float4* xv4 = (const float4*)xs;
    for (int rr = 0; rr < 16; ++rr) {
      const int n = n0 + (w << 4) + rr;
      const float4* wrow = (const float4*)(Wq + n * 1024);
      float p = 0.f;
#pragma unroll
      for (int c2 = 0; c2 < 4; ++c2) {
        float4 wv = wrow[lane + (c2 << 6)];
        float4 xv = xv4[lane + (c2 << 6)];
        p += xv.x * wv.x + xv.y * wv.y + xv.z * wv.z + xv.w * wv.w;
      }
#pragma unroll
      for (int off = 32; off; off >>= 1) p += __shfl_xor(p, off);
      if (lane == 0) ctx[b * 1024 + n] = p + bq[n];
    }
  }
}

// ---------- QKV projection: 128x128, double-buffered 1-barrier 2-phase ----------
template <bool SWP>
__device__ __forceinline__ void qkv_core128(
    const short* __restrict__ A, const short* __restrict__ W,
    const float* __restrict__ bias, short* __restrict__ out,
    short* As, short* Bs, int m0, int n0) {
  const int tid = threadIdx.x;
  const int w = tid >> 6, lane = tid & 63;
  const int m15 = lane & 15, quad = lane >> 4;
  const int wr = w >> 1, wc = w & 1;

  f32x4 acc[4][4];
#pragma unroll
  for (int i = 0; i < 4; ++i)
#pragma unroll
    for (int j = 0; j < 4; ++j) { f32x4 zz = {0.f, 0.f, 0.f, 0.f}; acc[i][j] = zz; }

  const int srow = (w << 5) + (lane >> 2);
  const int sxor = (srow >> 1) & 3;
  const int scol = (((lane & 3) ^ sxor) << 3);
  const short* ga0 = A + (m0 + srow) * 1024 + scol;
  const short* ga1 = ga0 + 16 * 1024;
  const short* gb0 = W + (n0 + srow) * 1024 + scol;
  const short* gb1 = gb0 + 16 * 1024;
  short* la0 = &As[srow * 32 + ((lane & 3) << 3)];
  short* la1 = la0 + 512;
  short* lb0 = &Bs[srow * 32 + ((lane & 3) << 3)];
  short* lb1 = lb0 + 512;

  async16(ga0, la0); async16(ga1, la1);
  async16(gb0, lb0); async16(gb1, lb1);
  __syncthreads();

  for (int kt = 0; kt < 32; ++kt) {
    const int buf = kt & 1;
    if (kt < 31) {
      const int nb = (buf ^ 1) << 12;
      const int off = (kt + 1) << 5;
      async16(ga0 + off, la0 + nb); async16(ga1 + off, la1 + nb);
      async16(gb0 + off, lb0 + nb); async16(gb1 + off, lb1 + nb);
    }
    const short* Ab = As + (buf << 12);
    const short* Bb = Bs + (buf << 12);
    bf16x8 a[4], b[4];
#pragma unroll
    for (int i = 0; i < 4; ++i) {
      const int ra = (wr << 6) + (i << 4) + m15;
      a[i] = *(const bf16x8*)(&Ab[ra * 32 + ((quad ^ ((ra >> 1) & 3)) << 3)]);
    }
#pragma unroll
    for (int j = 0; j < 4; ++j) {
      const int rb = (wc << 6) + (j << 4) + m15;
      b[j] = *(const bf16x8*)(&Bb[rb * 32 + ((quad ^ ((rb >> 1) & 3)) << 3)]);
    }
#pragma unroll
    for (int i = 0; i < 4; ++i)
#pragma unroll
      for (int j = 0; j < 4; ++j) {
        if (SWP) acc[i][j] = MFMA_BF16(b[j], a[i], acc[i][j]);
        else     acc[i][j] = MFMA_BF16(a[i], b[j], acc[i][j]);
      }
    if (kt < 31) __syncthreads();
  }

  if (SWP) {
#pragma unroll
    for (int j = 0; j < 4; ++j) {
      const int n = n0 + (wc << 6) + (j << 4) + (quad << 2);
      const float4 bv = *(const float4*)(bias + n);
      const int hh = n >> 6, dk0 = n & 63;
#pragma unroll
      for (int i = 0; i < 4; ++i) {
        const int m = m0 + (wr << 6) + (i << 4) + m15;
        const int bb = m >> 10, tt = m & 1023;
        uint2 st;
        st.x = pack2bf(acc[i][j][0] + bv.x, acc[i][j][1] + bv.y);
        st.y = pack2bf(acc[i][j][2] + bv.z, acc[i][j][3] + bv.w);
        *(uint2*)(out + (((bb << 4) + hh) << 16) + (tt << 6) + dk0) = st;
      }
    }
  } else {
#pragma unroll
    for (int j = 0; j < 4; ++j) {
      const int n = n0 + (wc << 6) + (j << 4) + m15;
      const float bv = bias[n];
      const int hh = n >> 6, dk = n & 63;
#pragma unroll
      for (int i = 0; i < 4; ++i) {
        const int m = m0 + (wr << 6) + (i << 4) + (quad << 2);
        const int bb = m >> 10, t0 = m & 1023;
        uint2 st;
        st.x = pack2bf(acc[i][j][0] + bv, acc[i][j][1] + bv);
        st.y = pack2bf(acc[i][j][2] + bv, acc[i][j][3] + bv);
        *(uint2*)(out + (((bb << 4) + hh) << 16) + (dk << 10) + t0) = st;
      }
    }
  }
}

// Fused launch: blocks 0..767 = QKV GEMM tiles; block 768 = gates finisher
__global__ __launch_bounds__(256) void gemm_qkv(
    const short* __restrict__ xb,
    const short* __restrict__ Wqb, const short* __restrict__ Wkb, const short* __restrict__ Wvb,
    const float* __restrict__ bq, const float* __restrict__ bk, const float* __restrict__ bv,
    short* __restrict__ Qh, short* __restrict__ Kh, short* __restrict__ Vt,
    const float* __restrict__ ctx, const float* __restrict__ Wg1,
    const float* __restrict__ bg1, const float* __restrict__ Wg2,
    const float* __restrict__ bg2, float* __restrict__ gates,
    float* __restrict__ u_out) {
  __shared__ short As[8192];   // 2 x (128x32) bf16
  __shared__ short Bs[8192];
  const int bid = blockIdx.x;
  if (bid < 768) {
    const int z = bid >> 8;
    const int r = bid & 255;
    const int m0 = (r & 31) << 7, n0 = (r >> 5) << 7;
    if (z == 0)      qkv_core128<true >(xb, Wqb, bq, Qh, As, Bs, m0, n0);
    else if (z == 1) qkv_core128<true >(xb, Wkb, bk, Kh, As, Bs, m0, n0);
    else             qkv_core128<false>(xb, Wvb, bv, Vt, As, Bs, m0, n0);
    return;
  }
  // ---- gates finisher (reuses As for reduction scratch) ----
  float* red = (float*)As;
  const int tid = threadIdx.x, w = tid >> 6, lane = tid & 63;
  for (int b = 0; b < 4; ++b) {
    float4 cv = ((const float4*)(ctx + b * 1024))[tid];
    float4 w1 = ((const float4*)Wg1)[tid];
    float4 w2 = ((const float4*)Wg2)[tid];
    float p1 = cv.x * w1.x + cv.y * w1.y + cv.z * w1.z + cv.w * w1.w;
    float p2 = cv.x * w2.x + cv.y * w2.y + cv.z * w2.z + cv.w * w2.w;
#pragma unroll
    for (int off = 32; off; off >>= 1) { p1 += __shfl_xor(p1, off); p2 += __shfl_xor(p2, off); }
    if (lane == 0) { red[w] = p1; red[8 + w] = p2; }
    __syncthreads();
    if (tid == 0) {
      float g1 = red[0] + red[1] + red[2] + red[3] + bg1[0];
      float g2 = red[8] + red[9] + red[10] + red[11] + bg2[0];
      float q1 = 1.f / (1.f + expf(-g1));
      float q2 = 1.f / (1.f + expf(-g2));
      float c = fminf(fmaxf(q1 * q2, 1e-8f), 1.0f);
      gates[b * 2 + 0] = c;
      gates[b * 2 + 1] = (c < 0.3f ? c : 1.0f) * 0.125f * 1.4426950408889634f;
      u_out[b] = 1.0f - c;
    }
    __syncthreads();
  }
}

// ---------- output projection: 64x128 tile dbuf -> 512 blocks (2/CU) ----------
__global__ __launch_bounds__(256) void gemm_out(const short* __restrict__ Ab_,
                                                const short* __restrict__ Wo,
                                                const float* __restrict__ bo,
                                                float* __restrict__ Cout) {
  const int m0 = blockIdx.x << 6;
  const int n0 = blockIdx.y << 7;
  const int tid = threadIdx.x;
  const int w = tid >> 6, lane = tid & 63;
  const int m15 = lane & 15, quad = lane >> 4;
  const int wr = w >> 1, wc = w & 1;

  __shared__ short As[4096];   // 2 x (64x32)
  __shared__ short Bs[8192];   // 2 x (128x32)

  f32x4 acc[2][4];
#pragma unroll
  for (int i = 0; i < 2; ++i)
#pragma unroll
    for (int j = 0; j < 4; ++j) { f32x4 zz = {0.f, 0.f, 0.f, 0.f}; acc[i][j] = zz; }

  const int arow = (w << 4) + (lane >> 2);               // 0..63
  const int axor = (arow >> 1) & 3;
  const short* gaA = Ab_ + (m0 + arow) * 1024 + (((lane & 3) ^ axor) << 3);
  short* laA = &As[arow * 32 + ((lane & 3) << 3)];
  const int brow = (w << 5) + (lane >> 2);               // rows brow, brow+16
  const int bxor = (brow >> 1) & 3;
  const short* gb0 = Wo + (n0 + brow) * 1024 + (((lane & 3) ^ bxor) << 3);
  const short* gb1 = gb0 + 16 * 1024;
  short* lb0 = &Bs[brow * 32 + ((lane & 3) << 3)];
  short* lb1 = lb0 + 512;

  async16(gaA, laA);
  async16(gb0, lb0); async16(gb1, lb1);
  __syncthreads();

  for (int kt = 0; kt < 32; ++kt) {
    const int buf = kt & 1;
    if (kt < 31) {
      const int off = (kt + 1) << 5;
      async16(gaA + off, laA + ((buf ^ 1) << 11));
      async16(gb0 + off, lb0 + ((buf ^ 1) << 12));
      async16(gb1 + off, lb1 + ((buf ^ 1) << 12));
    }
    const short* Ab = As + (buf << 11);
    const short* Bb = Bs + (buf << 12);
    bf16x8 a[2], b[4];
#pragma unroll
    for (int i = 0; i < 2; ++i) {
      const int ra = (wr << 5) + (i << 4) + m15;
      a[i] = *(const bf16x8*)(&Ab[ra * 32 + ((quad ^ ((ra >> 1) & 3)) << 3)]);
    }
#pragma unroll
    for (int j = 0; j < 4; ++j) {
      const int rb = (wc << 6) + (j << 4) + m15;
      b[j] = *(const bf16x8*)(&Bb[rb * 32 + ((quad ^ ((rb >> 1) & 3)) << 3)]);
    }
#pragma unroll
    for (int i = 0; i < 2; ++i)
#pragma unroll
      for (int j = 0; j < 4; ++j)
        acc[i][j] = MFMA_BF16(a[i], b[j], acc[i][j]);
    if (kt < 31) __syncthreads();
  }

#pragma unroll
  for (int j = 0; j < 4; ++j) {
    const int n = n0 + (wc << 6) + (j << 4) + m15;
    const float bb_ = bo[n];
#pragma unroll
    for (int i = 0; i < 2; ++i) {
      const int mb = m0 + (wr << 5) + (i << 4) + (quad << 2);
#pragma unroll
      for (int r = 0; r < 4; ++r)
        Cout[(mb + r) * 1024 + n] = acc[i][j][r] + bb_;
    }
  }
}

// ---------- flash attention: QBLK=64, defer-PV, fused meanV, 4 blocks/CU ----------
// Iter t: STAGE(t+1) | QK[t] | PV[t-1] (pf_prev regs, Vs[(t-1)%3]) | softmax[t].
__global__ __launch_bounds__(256, 4) void attn_k(const short* __restrict__ Qh,
                                                 const short* __restrict__ Kh,
                                                 const short* __restrict__ Vt,
                                                 const float* __restrict__ gates,
                                                 short* __restrict__ attnb) {
  const int bh = blockIdx.x;
  const int b = bh >> 4, h = bh & 15;
  const int q0 = blockIdx.y << 6;
  const int tid = threadIdx.x;
  const int w = tid >> 6, lane = tid & 63;
  const int m15 = lane & 15, quad = lane >> 4;

  __shared__ short Ks[2][4096];  // [64 k][64 d], 8-short chunks XOR-swizzled by row&7
  __shared__ short Vs[3][4096];  // [64 d][64 t], same swizzle, triple-buffered

  const short* ksrc = Kh + bh * 65536;
  const short* vsrc = Vt + bh * 65536;

  const float sl = gates[b * 2 + 1];

  const short* qsrc = Qh + ((bh << 10) + q0 + (w << 4) + m15) * 64;
  const bf16x8 qb0 = *(const bf16x8*)(qsrc + (quad << 3));
  const bf16x8 qb1 = *(const bf16x8*)(qsrc + 32 + (quad << 3));

  const bf16x8 vone = {0x3F80, 0x3F80, 0x3F80, 0x3F80, 0x3F80, 0x3F80, 0x3F80, 0x3F80};

  const int off0 = tid, off1 = tid + 256;
  const int r0 = off0 >> 3, cb0 = (off0 & 7) ^ (r0 & 7);
  const int r1 = off1 >> 3, cb1 = (off1 & 7) ^ (r1 & 7);

#define STAGE(kv, kb, vb)                                                      \
  do {                                                                         \
    async16(ksrc + (((kv) << 6) + r0) * 64 + (cb0 << 3), &Ks[kb][off0 << 3]);  \
    async16(ksrc + (((kv) << 6) + r1) * 64 + (cb1 << 3), &Ks[kb][off1 << 3]);  \
    async16(vsrc + r0 * 1024 + ((kv) << 6) + (cb0 << 3), &Vs[vb][off0 << 3]);  \
    async16(vsrc + r1 * 1024 + ((kv) << 6) + (cb1 << 3), &Vs[vb][off1 << 3]);  \
  } while (0)

  STAGE(0, 0, 0);

  float lsum = 0.f;
  f32x4 oA[4], o_mv[4];
#pragma unroll
  for (int jd = 0; jd < 4; ++jd) {
    f32x4 zz = {0.f, 0.f, 0.f, 0.f};
    oA[jd] = zz; o_mv[jd] = zz;
  }

  const int srcA = ((quad & 1) << 5) + m15;
  const int srcB = srcA + 16;
  const bool selhi = (quad & 2) != 0;

#define BUILD_PF(pf, pk)                                                       \
  do {                                                                         \
    _Pragma("unroll")                                                          \
    for (int Hh = 0; Hh < 2; ++Hh) {                                           \
      uint32_t f[4];                                                           \
      _Pragma("unroll")                                                        \
      for (int rp = 0; rp < 2; ++rp) {                                         \
        uint32_t alo = (uint32_t)__shfl((int)pk[2 * Hh][rp], srcA);            \
        uint32_t ahi = (uint32_t)__shfl((int)pk[2 * Hh + 1][rp], srcA);        \
        uint32_t blo = (uint32_t)__shfl((int)pk[2 * Hh][rp], srcB);            \
        uint32_t bhi = (uint32_t)__shfl((int)pk[2 * Hh + 1][rp], srcB);        \
        f[rp]     = selhi ? ahi : alo;                                         \
        f[2 + rp] = selhi ? bhi : blo;                                         \
      }                                                                        \
      pf[Hh] = *(bf16x8*)f;                                                    \
    }                                                                          \
  } while (0)

#define PV_STEP(Vb, pfa)                                                       \
  do {                                                                         \
    _Pragma("unroll")                                                          \
    for (int jd = 0; jd < 4; ++jd) {                                           \
      const int row = (jd << 4) + m15;                                         \
      const int sw = row & 7;                                                  \
      bf16x8 v0 = *(const bf16x8*)((Vb) + (row << 6) + ((quad ^ sw) << 3));    \
      bf16x8 v1 = *(const bf16x8*)((Vb) + (row << 6) + (((quad + 4) ^ sw) << 3)); \
      oA[jd] = MFMA_BF16(v0, pfa[0], oA[jd]);                                  \
      oA[jd] = MFMA_BF16(v1, pfa[1], oA[jd]);                                  \
      o_mv[jd] = MFMA_BF16(v0, vone, o_mv[jd]);                                \
      o_mv[jd] = MFMA_BF16(v1, vone, o_mv[jd]);                                \
    }                                                                          \
  } while (0)

  bf16x8 pfp[2];
  pfp[0] = (bf16x8){0, 0, 0, 0, 0, 0, 0, 0};
  pfp[1] = pfp[0];

  for (int kv = 0; kv < 16; ++kv) {
    __syncthreads();  // Ks[kv&1]/Vs[kv%3] landed; prior reads done
    if (kv < 15) STAGE(kv + 1, (kv + 1) & 1, (kv + 1) % 3);
    const short* Kb = &Ks[kv & 1][0];

    // --- QK[kv] ---
    f32x4 sA[4];
#pragma unroll
    for (int s = 0; s < 4; ++s) {
      const int row = (s << 4) + m15;
      const int sw = row & 7;
      bf16x8 a0 = *(const bf16x8*)(Kb + (row << 6) + ((quad ^ sw) << 3));
      bf16x8 a1 = *(const bf16x8*)(Kb + (row << 6) + (((quad + 4) ^ sw) << 3));
      f32x4 zz = {0.f, 0.f, 0.f, 0.f};
      zz = MFMA_BF16(a0, qb0, zz);
      zz = MFMA_BF16(a1, qb1, zz);
      sA[s] = zz;
    }

    // --- PV[kv-1] (independent of QK[kv] and softmax below) ---
    if (kv > 0) {
      const short* Vb = &Vs[(kv - 1) % 3][0];
      PV_STEP(Vb, pfp);
    }

    // --- softmax[kv] ---
    uint32_t pk[4][2];
#pragma unroll
    for (int s = 0; s < 4; ++s) {
      float p0 = fexp2(sA[s][0] * sl);
      float p1 = fexp2(sA[s][1] * sl);
      float p2 = fexp2(sA[s][2] * sl);
      float p3 = fexp2(sA[s][3] * sl);
      lsum += (p0 + p1) + (p2 + p3);
      pk[s][0] = pack2bf(p0, p1);
      pk[s][1] = pack2bf(p2, p3);
    }

    bf16x8 pf[2];
    BUILD_PF(pf, pk);
    pfp[0] = pf[0]; pfp[1] = pf[1];
  }

  // --- epilogue PV[15]: Vs[0], staged at kv=14, drained by kv=15 barrier ---
  {
    const short* Vb = &Vs[15 % 3][0];
    PV_STEP(Vb, pfp);
  }
#undef STAGE
#undef BUILD_PF
#undef PV_STEP

  float l = lsum;
  l += __shfl_xor(l, 16);
  l += __shfl_xor(l, 32);

  const float cg = gates[b * 2 + 0];
  const float sc0 = cg / l;
  const float coef = (1.0f - cg) * (1.0f / 1024.0f);  // o_mv holds raw sums over t
  const int qrow = q0 + (w << 4) + m15;
  short* orow = attnb + ((b << 10) + qrow) * 1024 + (h << 6);
#pragma unroll
  for (int jd = 0; jd < 4; ++jd) {
    uint2 st;
    st.x = pack2bf(sc0 * oA[jd][0] + coef * o_mv[jd][0],
                   sc0 * oA[jd][1] + coef * o_mv[jd][1]);
    st.y = pack2bf(sc0 * oA[jd][2] + coef * o_mv[jd][2],
                   sc0 * oA[jd][3] + coef * o_mv[jd][3]);
    *(uint2*)(orow + (jd << 4) + (quad << 2)) = st;
  }
}

// ---------- launch ----------
extern "C" void kernel_launch(void* const* d_in, const int* in_sizes, int n_in,
                              void* d_out, int out_size, void* d_ws, size_t ws_size,
                              hipStream_t stream) {
  const float* x   = (const float*)d_in[0];
  const float* Wq  = (const float*)d_in[1];
  const float* bq  = (const float*)d_in[2];
  const float* Wk  = (const float*)d_in[3];
  const float* bk  = (const float*)d_in[4];
  const float* Wv  = (const float*)d_in[5];
  const float* bv  = (const float*)d_in[6];
  const float* Wo  = (const float*)d_in[7];
  const float* bo  = (const float*)d_in[8];
  const float* Wg1 = (const float*)d_in[9];
  const float* bg1 = (const float*)d_in[10];
  const float* Wg2 = (const float*)d_in[11];
  const float* bg2 = (const float*)d_in[12];
  float* out = (float*)d_out;

  char* ws = (char*)d_ws;
  short* xb   = (short*)(ws + 0);          //  8 MB  x bf16 [4096][1024]
  short* Wqb  = (short*)(ws + 8388608);    //  2 MB
  short* Wkb  = (short*)(ws + 10485760);   //  2 MB
  short* Wvb  = (short*)(ws + 12582912);   //  2 MB
  short* Wob  = (short*)(ws + 14680064);   //  2 MB
  short* Qh   = (short*)(ws + 16777216);   //  8 MB  [BH][T][64]
  short* Kh   = (short*)(ws + 25165824);   //  8 MB  [BH][T][64]
  short* Vt   = (short*)(ws + 33554432);   //  8 MB  [BH][64][T]
  short* attb = (short*)(ws + 41943040);   //  8 MB  [4096][1024]
  float* ctx  = (float*)(ws + 50331648);   // 16 KB
  float* gat  = (float*)(ws + 50348032);   // 32 B   [B][{c, scale*log2e}]

  prep_k<<<8256, 256, 0, stream>>>(x, Wq, Wk, Wv, Wo, bq,
                                   xb, Wqb, Wkb, Wvb, Wob, ctx);
  gemm_qkv<<<769, 256, 0, stream>>>(xb, Wqb, Wkb, Wvb, bq, bk, bv,
                                    Qh, Kh, Vt,
                                    ctx, Wg1, bg1, Wg2, bg2, gat,
                                    out + 4194304);
  attn_k<<<dim3(64, 16), 256, 0, stream>>>(Qh, Kh, Vt, gat, attb);
  gemm_out<<<dim3(64, 8), 256, 0, stream>>>(attb, Wob, bo, out);
}